// Round 9
// baseline (77.953 us; speedup 1.0000x reference)
//
#include <hip/hip_runtime.h>
#include <math.h>

#define B 256
#define S 512
#define H 768
#define H4 (H / 4)      // 192 float4 columns
#define NQ 4            // quarter-slabs per batch
#define QROWS (S / NQ)  // 128 rows per quarter
#define NSMALL 64       // n = B/4

typedef float f32x4 __attribute__((ext_vector_type(4)));

__device__ __forceinline__ float waveReduceSum(float v) {
    v += __shfl_down(v, 32);
    v += __shfl_down(v, 16);
    v += __shfl_down(v, 8);
    v += __shfl_down(v, 4);
    v += __shfl_down(v, 2);
    v += __shfl_down(v, 1);
    return v;
}

// Stage A: 1024 blocks = (batch b, quarter qq). 768 threads = 192 float4-cols
// x 4 row-groups. Each block streams 128 contiguous rows (384 KB) with
// non-temporal float4 loads, LDS-reduces the 4 row-groups, writes one
// partial f32x4 per column. 4 blocks/CU -> load balancing + deeper MLP.
// (mask cancels algebraically in the L2 normalize; never read.)
__global__ void pool_partial_k(const float* __restrict__ lhs,
                               f32x4* __restrict__ part) {
    const int blk = blockIdx.x;
    const int b   = blk >> 2;       // 0..255
    const int qq  = blk & 3;        // 0..3
    const int t   = threadIdx.x;    // 0..767
    const int col = t % H4;         // float4 column
    const int rg  = t / H4;         // row-group 0..3 (192 = 3 waves each)

    __shared__ f32x4 red[3][H4];

    const f32x4* __restrict__ src =
        reinterpret_cast<const f32x4*>(lhs) +
        ((size_t)b * S + (size_t)qq * QROWS) * H4;
    f32x4 acc = {0.f, 0.f, 0.f, 0.f};
#pragma unroll 16
    for (int s = 0; s < QROWS / 4; ++s) {
        f32x4 v = __builtin_nontemporal_load(&src[(size_t)(4 * s + rg) * H4 + col]);
        acc += v;
    }
    if (rg > 0) red[rg - 1][col] = acc;
    __syncthreads();

    if (rg == 0) {
        f32x4 p = acc;
        p += red[0][col];
        p += red[1][col];
        p += red[2][col];
        part[((size_t)qq * B + b) * H4 + col] = p;
    }
}

// Stage B: 256 blocks x 192 threads (3 waves). Combine the 4 quarter
// partials, L2-normalize, write z[b].
__global__ void pool_norm_k(const f32x4* __restrict__ part,
                            float* __restrict__ z) {
    const int b = blockIdx.x;       // 0..255
    const int t = threadIdx.x;      // 0..191 (= col)

    __shared__ float sq[3];

    f32x4 p = part[((size_t)0 * B + b) * H4 + t];
    p += part[((size_t)1 * B + b) * H4 + t];
    p += part[((size_t)2 * B + b) * H4 + t];
    p += part[((size_t)3 * B + b) * H4 + t];

    float s2 = p.x * p.x + p.y * p.y + p.z * p.z + p.w * p.w;
    float ws2 = waveReduceSum(s2);
    if ((t & 63) == 0) sq[t >> 6] = ws2;
    __syncthreads();
    const float inv_n = 1.0f / sqrtf(sq[0] + sq[1] + sq[2]);
    p *= inv_n;
    reinterpret_cast<f32x4*>(z + (size_t)b * H)[t] = p;
}

// Kernel 3: 256 blocks = (row i 0..63) x (col-chunk jc 0..3 of 64 cols).
// Thread t: column col = t&63 (global j = jc*64+col), quarter q = t>>6.
// Each thread computes a 192-elem partial dot; LDS-combine to full dots.
// logits in [-2,2] -> exp without max-subtraction is safe (sum <= 255*e^2).
// Block writes: sp[i*4+jc] = sum_j exp(logit_ij) (diag masked);
// jc==0 also writes pairneg[i] = sum_{j>i,j<64} (-logit_ij).
__global__ void row_part_k(const float* __restrict__ z,
                           float* __restrict__ sp,
                           float* __restrict__ pairneg) {
    const int i  = blockIdx.x >> 2;
    const int jc = blockIdx.x & 3;
    const int t  = threadIdx.x;    // 0..255
    const int col = t & 63;
    const int q   = t >> 6;
    const int j   = jc * 64 + col;

    __shared__ float zi[H];
    __shared__ float pd[4][64];

    zi[t]       = z[(size_t)i * H + t];
    zi[t + 256] = z[(size_t)i * H + 256 + t];
    zi[t + 512] = z[(size_t)i * H + 512 + t];
    __syncthreads();

    // partial dot: elems q*192 .. q*192+191 (48 float4)
    const float4* __restrict__ zj4 =
        reinterpret_cast<const float4*>(z + (size_t)j * H) + q * 48;
    const float4* zi4 = reinterpret_cast<const float4*>(zi) + q * 48;
    float d0 = 0.f, d1 = 0.f;
#pragma unroll 8
    for (int k = 0; k < 48; k += 2) {
        float4 a  = zi4[k];     float4 c1 = zj4[k];
        float4 a2 = zi4[k + 1]; float4 c2 = zj4[k + 1];
        d0 += a.x * c1.x + a.y * c1.y + a.z * c1.z + a.w * c1.w;
        d1 += a2.x * c2.x + a2.y * c2.y + a2.z * c2.z + a2.w * c2.w;
    }
    pd[q][col] = d0 + d1;
    __syncthreads();

    if (t < 64) {  // wave 0 finalizes; col == t here
        const float dot = pd[0][t] + pd[1][t] + pd[2][t] + pd[3][t];
        const float logit = dot * 2.0f;  // / TAU
        const float ev = (j == i) ? 0.f : expf(logit);
        float s = waveReduceSum(ev);
        if (t == 0) sp[i * 4 + jc] = s;
        if (jc == 0) {
            const float term = (t > i) ? -logit : 0.f;
            float ts = waveReduceSum(term);
            if (t == 0) pairneg[i] = ts;
        }
    }
}

// Kernel 4: one wave. rowloss_i = (63-i)*log(sum_c sp[i][c]) + pairneg[i].
__global__ void final_k(const float* __restrict__ sp,
                        const float* __restrict__ pairneg,
                        float* __restrict__ out) {
    const int i = threadIdx.x;  // 0..63
    const float s = sp[i * 4] + sp[i * 4 + 1] + sp[i * 4 + 2] + sp[i * 4 + 3];
    const float logden = logf(s);
    const float row = (float)(NSMALL - 1 - i) * logden + pairneg[i];
    float tot = waveReduceSum(row);
    if (i == 0) {
        out[0] = (-2.0f / (float)NSMALL) * (float)(NSMALL - 1) * tot;
    }
}

extern "C" void kernel_launch(void* const* d_in, const int* in_sizes, int n_in,
                              void* d_out, int out_size, void* d_ws, size_t ws_size,
                              hipStream_t stream) {
    const float* lhs  = (const float*)d_in[0];   // [256,512,768] f32
    float* out = (float*)d_out;                  // scalar f32
    float* ws  = (float*)d_ws;

    f32x4* part    = (f32x4*)ws;                       // NQ*B*H4 f32x4 = 3.1 MB
    float* z       = ws + (size_t)NQ * B * H;          // B*H = 196,608 f
    float* sp      = z + (size_t)B * H;                // 64*4 = 256 f
    float* pairneg = sp + NSMALL * 4;                  // 64 f

    pool_partial_k<<<B * NQ, H, 0, stream>>>(lhs, part);
    pool_norm_k<<<B, H4, 0, stream>>>(part, z);
    row_part_k<<<NSMALL * 4, 256, 0, stream>>>(z, sp, pairneg);
    final_k<<<1, 64, 0, stream>>>(sp, pairneg, out);
}

// Round 10
// 73.954 us; speedup vs baseline: 1.0541x; 1.0541x over previous
//
#include <hip/hip_runtime.h>
#include <math.h>

#define B 256
#define S 512
#define H 768
#define H4 (H / 4)      // 192 float4 columns
#define NSMALL 64       // n = B/4

typedef float f32x4 __attribute__((ext_vector_type(4)));

__device__ __forceinline__ float waveReduceSum(float v) {
    v += __shfl_down(v, 32);
    v += __shfl_down(v, 16);
    v += __shfl_down(v, 8);
    v += __shfl_down(v, 4);
    v += __shfl_down(v, 2);
    v += __shfl_down(v, 1);
    return v;
}

// Kernel 1: one block per batch (1 block/CU). 768 threads = 192 float4-cols
// x 4 row-groups. Streams the batch's 512x768 slab (1.57 MB) coalesced with
// NON-TEMPORAL loads (zero-reuse data: ~12% faster than cached path, R7),
// LDS-reduces the 4 row-groups, L2-normalizes, writes z[b].
// NOTE: the input mask cancels algebraically: z = (sum/m)/|sum/m| = sum/|sum|,
// so the mask is never read (identical math; R8 measured win).
// R9 measured: splitting this into 4 blocks/batch + combine kernel REGRESSES
// (-4.6 us) — the kernel is read-BW-bound at ~6.2 TB/s, not balance-limited.
__global__ void pool_z_k(const float* __restrict__ lhs,
                         float* __restrict__ z) {
    const int b = blockIdx.x;       // 0..255
    const int t = threadIdx.x;      // 0..767
    const int col = t % H4;         // float4 column
    const int rg  = t / H4;         // row-group 0..3 (wave-aligned: 192 = 3*64)

    __shared__ f32x4 red[3][H4];    // rg 1..3 partials
    __shared__ float sq[3];         // sumsq wave sums (waves 0..2)

    const f32x4* __restrict__ src =
        reinterpret_cast<const f32x4*>(lhs) + (size_t)b * S * H4;
    f32x4 acc = {0.f, 0.f, 0.f, 0.f};
#pragma unroll 16
    for (int s = 0; s < S / 4; ++s) {
        f32x4 v = __builtin_nontemporal_load(&src[(size_t)(4 * s + rg) * H4 + col]);
        acc += v;
    }
    if (rg > 0) red[rg - 1][col] = acc;
    __syncthreads();

    if (rg == 0) {
        f32x4 p = acc;
        p += red[0][col];
        p += red[1][col];
        p += red[2][col];
        float s2 = p.x * p.x + p.y * p.y + p.z * p.z + p.w * p.w;
        float ws2 = waveReduceSum(s2);          // waves 0..2 full
        if ((t & 63) == 0) sq[t >> 6] = ws2;
        __builtin_amdgcn_s_barrier();           // full-block barrier
        const float inv_n = 1.0f / sqrtf(sq[0] + sq[1] + sq[2]);
        p *= inv_n;
        reinterpret_cast<f32x4*>(z + (size_t)b * H)[col] = p;
    } else {
        __builtin_amdgcn_s_barrier();
    }
}

// Kernel 2: 256 blocks = (row i 0..63) x (col-chunk jc 0..3 of 64 cols).
// Thread t: column col = t&63 (global j = jc*64+col), quarter q = t>>6.
// Each thread computes a 192-elem partial dot; LDS-combine to full dots.
// logits in [-2,2] -> exp without max-subtraction is safe (sum <= 255*e^2).
// Block writes: sp[i*4+jc] = sum_j exp(logit_ij) (diag masked);
// jc==0 also writes pairneg[i] = sum_{j>i,j<64} (-logit_ij).
__global__ void row_part_k(const float* __restrict__ z,
                           float* __restrict__ sp,
                           float* __restrict__ pairneg) {
    const int i  = blockIdx.x >> 2;
    const int jc = blockIdx.x & 3;
    const int t  = threadIdx.x;    // 0..255
    const int col = t & 63;
    const int q   = t >> 6;
    const int j   = jc * 64 + col;

    __shared__ float zi[H];
    __shared__ float pd[4][64];

    zi[t]       = z[(size_t)i * H + t];
    zi[t + 256] = z[(size_t)i * H + 256 + t];
    zi[t + 512] = z[(size_t)i * H + 512 + t];
    __syncthreads();

    // partial dot: elems q*192 .. q*192+191 (48 float4)
    const float4* __restrict__ zj4 =
        reinterpret_cast<const float4*>(z + (size_t)j * H) + q * 48;
    const float4* zi4 = reinterpret_cast<const float4*>(zi) + q * 48;
    float d0 = 0.f, d1 = 0.f;
#pragma unroll 8
    for (int k = 0; k < 48; k += 2) {
        float4 a  = zi4[k];     float4 c1 = zj4[k];
        float4 a2 = zi4[k + 1]; float4 c2 = zj4[k + 1];
        d0 += a.x * c1.x + a.y * c1.y + a.z * c1.z + a.w * c1.w;
        d1 += a2.x * c2.x + a2.y * c2.y + a2.z * c2.z + a2.w * c2.w;
    }
    pd[q][col] = d0 + d1;
    __syncthreads();

    if (t < 64) {  // wave 0 finalizes; col == t here
        const float dot = pd[0][t] + pd[1][t] + pd[2][t] + pd[3][t];
        const float logit = dot * 2.0f;  // / TAU
        const float ev = (j == i) ? 0.f : expf(logit);
        float s = waveReduceSum(ev);
        if (t == 0) sp[i * 4 + jc] = s;
        if (jc == 0) {
            const float term = (t > i) ? -logit : 0.f;
            float ts = waveReduceSum(term);
            if (t == 0) pairneg[i] = ts;
        }
    }
}

// Kernel 3: one wave. rowloss_i = (63-i)*log(sum_c sp[i][c]) + pairneg[i].
__global__ void final_k(const float* __restrict__ sp,
                        const float* __restrict__ pairneg,
                        float* __restrict__ out) {
    const int i = threadIdx.x;  // 0..63
    const float s = sp[i * 4] + sp[i * 4 + 1] + sp[i * 4 + 2] + sp[i * 4 + 3];
    const float logden = logf(s);
    const float row = (float)(NSMALL - 1 - i) * logden + pairneg[i];
    float tot = waveReduceSum(row);
    if (i == 0) {
        out[0] = (-2.0f / (float)NSMALL) * (float)(NSMALL - 1) * tot;
    }
}

extern "C" void kernel_launch(void* const* d_in, const int* in_sizes, int n_in,
                              void* d_out, int out_size, void* d_ws, size_t ws_size,
                              hipStream_t stream) {
    const float* lhs  = (const float*)d_in[0];   // [256,512,768] f32
    float* out = (float*)d_out;                  // scalar f32
    float* ws  = (float*)d_ws;

    float* z       = ws;                         // B*H = 196,608 f
    float* sp      = z + (size_t)B * H;          // 64*4 = 256 f
    float* pairneg = sp + NSMALL * 4;            // 64 f

    pool_z_k<<<B, H, 0, stream>>>(lhs, z);
    row_part_k<<<NSMALL * 4, 256, 0, stream>>>(z, sp, pairneg);
    final_k<<<1, 64, 0, stream>>>(sp, pairneg, out);
}